// Round 1
// baseline (90.658 us; speedup 1.0000x reference)
//
#include <hip/hip_runtime.h>
#include <math.h>

// LearnableLPDistance: A,B [1,8,512,64] f32, p_raw [1] f32.
// p = softplus(p_raw)+1e-10; Lp-normalize rows; out[h,n,m] = 1 - 0.5*Lp(An[n]-Bn[m]).

#define EPSF 1e-10f
#define NHEAD 8
#define NROW  512
#define DDIM  64
#define TSTRIDE 68  // LDS row stride in dwords: 16B-aligned float4 rows, banks spread

__device__ __forceinline__ float hw_log2(float x) { return __builtin_amdgcn_logf(x); }   // v_log_f32 (log2)
__device__ __forceinline__ float hw_exp2(float x) { return __builtin_amdgcn_exp2f(x); }  // v_exp_f32 (exp2)
// x >= 0; x==0 -> log2(0)=-inf -> exp2(-inf)=0 (matches 0^p for p>0)
__device__ __forceinline__ float powp(float x, float p) { return hw_exp2(p * hw_log2(x)); }

__device__ __forceinline__ float softplusf(float x) {
    // numerically stable softplus: max(x,0) + log1p(exp(-|x|))
    return fmaxf(x, 0.0f) + log1pf(expf(-fabsf(x)));
}

// One wave per row; 8192 rows total (4096 A then 4096 B). Writes normalized rows to ws.
__global__ __launch_bounds__(256) void lp_norm_kernel(const float* __restrict__ A,
                                                      const float* __restrict__ B,
                                                      const float* __restrict__ p_raw,
                                                      float* __restrict__ ws) {
    const float p     = softplusf(p_raw[0]) + EPSF;
    const float inv_p = 1.0f / p;
    const int row  = blockIdx.x * 4 + (threadIdx.x >> 6);   // 4 waves/block
    const int lane = threadIdx.x & 63;
    const float* src = (row < 4096) ? (A + (size_t)row * DDIM)
                                    : (B + (size_t)(row - 4096) * DDIM);
    const float x = src[lane];
    float t = powp(fabsf(x), p);
    #pragma unroll
    for (int m = 1; m < 64; m <<= 1) t += __shfl_xor(t, m, 64);
    const float norm = powp(t, inv_p) + EPSF;
    ws[(size_t)row * DDIM + lane] = x / norm;
}

// 64x64 output tile per 256-thread block. grid = (8 m-tiles, 8 n-tiles, 8 heads).
__global__ __launch_bounds__(256) void lp_pair_kernel(const float* __restrict__ ws,
                                                      const float* __restrict__ p_raw,
                                                      float* __restrict__ out) {
    __shared__ float As[DDIM * TSTRIDE];  // [row 0..63][d 0..63], stride 68 dwords
    __shared__ float Bs[DDIM * TSTRIDE];

    const float p     = softplusf(p_raw[0]) + EPSF;
    const float inv_p = 1.0f / p;

    const int h  = blockIdx.z;
    const int n0 = blockIdx.y * 64;
    const int m0 = blockIdx.x * 64;
    const float* An = ws + (size_t)h * NROW * DDIM;
    const float* Bn = ws + (size_t)4096 * DDIM + (size_t)h * NROW * DDIM;
    const int tid = threadIdx.x;

    // Stage both 64x64 tiles: 1024 float4 per tile, 4 per thread, coalesced global reads.
    #pragma unroll
    for (int k = 0; k < 4; ++k) {
        const int qq  = k * 256 + tid;
        const int row = qq >> 4;   // 0..63
        const int d4  = qq & 15;   // 0..15
        const float4 va = *reinterpret_cast<const float4*>(An + (size_t)(n0 + row) * DDIM + d4 * 4);
        const float4 vb = *reinterpret_cast<const float4*>(Bn + (size_t)(m0 + row) * DDIM + d4 * 4);
        *reinterpret_cast<float4*>(&As[row * TSTRIDE + d4 * 4]) = va;
        *reinterpret_cast<float4*>(&Bs[row * TSTRIDE + d4 * 4]) = vb;
    }
    __syncthreads();

    // Thread (tn,tm) covers rows {tn+16i} x cols {tm+16j}, i,j in 0..3 (strided mapping
    // keeps LDS reads <=2-way bank aliased and output stores in full 64B segments).
    const int tn = tid >> 4;   // 0..15
    const int tm = tid & 15;   // 0..15

    float acc[4][4];
    #pragma unroll
    for (int i = 0; i < 4; ++i)
        #pragma unroll
        for (int j = 0; j < 4; ++j) acc[i][j] = 0.0f;

    for (int d = 0; d < DDIM; d += 4) {
        float4 a[4], b[4];
        #pragma unroll
        for (int i = 0; i < 4; ++i)
            a[i] = *reinterpret_cast<const float4*>(&As[(tn + 16 * i) * TSTRIDE + d]);
        #pragma unroll
        for (int j = 0; j < 4; ++j)
            b[j] = *reinterpret_cast<const float4*>(&Bs[(tm + 16 * j) * TSTRIDE + d]);
        #pragma unroll
        for (int i = 0; i < 4; ++i) {
            #pragma unroll
            for (int j = 0; j < 4; ++j) {
                acc[i][j] += powp(fabsf(a[i].x - b[j].x), p);
                acc[i][j] += powp(fabsf(a[i].y - b[j].y), p);
                acc[i][j] += powp(fabsf(a[i].z - b[j].z), p);
                acc[i][j] += powp(fabsf(a[i].w - b[j].w), p);
            }
        }
    }

    float* outh = out + (size_t)h * NROW * NROW;
    #pragma unroll
    for (int i = 0; i < 4; ++i) {
        const int n = n0 + tn + 16 * i;
        #pragma unroll
        for (int j = 0; j < 4; ++j) {
            const int m = m0 + tm + 16 * j;
            const float dist = powp(acc[i][j], inv_p);
            outh[(size_t)n * NROW + m] = 1.0f - 0.5f * dist;
        }
    }
}

extern "C" void kernel_launch(void* const* d_in, const int* in_sizes, int n_in,
                              void* d_out, int out_size, void* d_ws, size_t ws_size,
                              hipStream_t stream) {
    const float* A     = (const float*)d_in[0];
    const float* B     = (const float*)d_in[1];
    const float* p_raw = (const float*)d_in[2];
    float* out = (float*)d_out;
    float* ws  = (float*)d_ws;   // [8192][64] normalized rows: An then Bn (2 MB)

    lp_norm_kernel<<<dim3(2048), dim3(256), 0, stream>>>(A, B, p_raw, ws);
    lp_pair_kernel<<<dim3(8, 8, 8), dim3(256), 0, stream>>>(ws, p_raw, out);
}

// Round 2
// 90.409 us; speedup vs baseline: 1.0028x; 1.0028x over previous
//
#include <hip/hip_runtime.h>
#include <math.h>

// LearnableLPDistance: A,B [1,8,512,64] f32, p_raw [1] f32.
// p = softplus(p_raw)+1e-10; Lp-normalize rows; out[h,n,m] = 1 - 0.5*Lp(An[n]-Bn[m]).

#define EPSF 1e-10f
#define NROW  512
#define DDIM  64
#define TSTRIDE 68   // LDS row stride in dwords (16B-aligned, spreads banks)
#define TB 32        // output tile: 32x32

__device__ __forceinline__ float hw_log2(float x) { return __builtin_amdgcn_logf(x); }   // v_log_f32
__device__ __forceinline__ float hw_exp2(float x) { return __builtin_amdgcn_exp2f(x); }  // v_exp_f32
// x >= 0; x==0 -> log2(0)=-inf -> exp2(-inf)=0 (matches 0^p, p>0)
__device__ __forceinline__ float powp(float x, float p) { return hw_exp2(p * hw_log2(x)); }

__device__ __forceinline__ float softplusf(float x) {
    return fmaxf(x, 0.0f) + log1pf(expf(-fabsf(x)));
}

// One wave per row; 8192 rows (4096 A then 4096 B). Writes normalized rows to ws.
__global__ __launch_bounds__(256) void lp_norm_kernel(const float* __restrict__ A,
                                                      const float* __restrict__ B,
                                                      const float* __restrict__ p_raw,
                                                      float* __restrict__ ws) {
    const float p     = softplusf(p_raw[0]) + EPSF;
    const float inv_p = 1.0f / p;
    const int row  = blockIdx.x * 4 + (threadIdx.x >> 6);
    const int lane = threadIdx.x & 63;
    const float* src = (row < 4096) ? (A + (size_t)row * DDIM)
                                    : (B + (size_t)(row - 4096) * DDIM);
    const float x = src[lane];
    float t = powp(fabsf(x), p);
    #pragma unroll
    for (int m = 1; m < 64; m <<= 1) t += __shfl_xor(t, m, 64);
    const float norm = powp(t, inv_p) + EPSF;
    ws[(size_t)row * DDIM + lane] = x / norm;
}

// 32x32 output tile per 256-thread block. grid = (16 m-tiles, 16 n-tiles, 8 heads)
// = 2048 blocks -> 8 blocks/CU co-resident (LDS 17.4 KB/block), 8 waves/SIMD target.
__global__ __launch_bounds__(256, 6) void lp_pair_kernel(const float* __restrict__ ws,
                                                         const float* __restrict__ p_raw,
                                                         float* __restrict__ out) {
    __shared__ float As[TB * TSTRIDE];   // [row 0..31][d 0..63]
    __shared__ float Bs[TB * TSTRIDE];

    const float p     = softplusf(p_raw[0]) + EPSF;
    const float inv_p = 1.0f / p;

    const int h  = blockIdx.z;
    const int n0 = blockIdx.y * TB;
    const int m0 = blockIdx.x * TB;
    const float* An = ws + (size_t)h * NROW * DDIM;
    const float* Bn = ws + (size_t)4096 * DDIM + (size_t)h * NROW * DDIM;
    const int tid = threadIdx.x;

    // Stage both 32x64 tiles: 512 float4 per tile, 2 per thread, coalesced.
    #pragma unroll
    for (int k = 0; k < 2; ++k) {
        const int qq  = k * 256 + tid;
        const int row = qq >> 4;   // 0..31
        const int d4  = qq & 15;   // 0..15
        const float4 va = *reinterpret_cast<const float4*>(An + (size_t)(n0 + row) * DDIM + d4 * 4);
        const float4 vb = *reinterpret_cast<const float4*>(Bn + (size_t)(m0 + row) * DDIM + d4 * 4);
        *reinterpret_cast<float4*>(&As[row * TSTRIDE + d4 * 4]) = va;
        *reinterpret_cast<float4*>(&Bs[row * TSTRIDE + d4 * 4]) = vb;
    }
    __syncthreads();

    // Thread (tn,tm) covers rows {tn, tn+16} x cols {tm, tm+16}.
    const int tn = tid >> 4;   // 0..15
    const int tm = tid & 15;   // 0..15

    float acc00 = 0.f, acc01 = 0.f, acc10 = 0.f, acc11 = 0.f;

    #pragma unroll
    for (int d = 0; d < DDIM; d += 4) {
        const float4 a0 = *reinterpret_cast<const float4*>(&As[tn * TSTRIDE + d]);
        const float4 a1 = *reinterpret_cast<const float4*>(&As[(tn + 16) * TSTRIDE + d]);
        const float4 b0 = *reinterpret_cast<const float4*>(&Bs[tm * TSTRIDE + d]);
        const float4 b1 = *reinterpret_cast<const float4*>(&Bs[(tm + 16) * TSTRIDE + d]);
        acc00 += powp(fabsf(a0.x - b0.x), p); acc00 += powp(fabsf(a0.y - b0.y), p);
        acc00 += powp(fabsf(a0.z - b0.z), p); acc00 += powp(fabsf(a0.w - b0.w), p);
        acc01 += powp(fabsf(a0.x - b1.x), p); acc01 += powp(fabsf(a0.y - b1.y), p);
        acc01 += powp(fabsf(a0.z - b1.z), p); acc01 += powp(fabsf(a0.w - b1.w), p);
        acc10 += powp(fabsf(a1.x - b0.x), p); acc10 += powp(fabsf(a1.y - b0.y), p);
        acc10 += powp(fabsf(a1.z - b0.z), p); acc10 += powp(fabsf(a1.w - b0.w), p);
        acc11 += powp(fabsf(a1.x - b1.x), p); acc11 += powp(fabsf(a1.y - b1.y), p);
        acc11 += powp(fabsf(a1.z - b1.z), p); acc11 += powp(fabsf(a1.w - b1.w), p);
    }

    float* outh = out + (size_t)h * NROW * NROW;
    const int n_lo = n0 + tn, n_hi = n0 + tn + 16;
    const int m_lo = m0 + tm, m_hi = m0 + tm + 16;
    outh[(size_t)n_lo * NROW + m_lo] = 1.0f - 0.5f * powp(acc00, inv_p);
    outh[(size_t)n_lo * NROW + m_hi] = 1.0f - 0.5f * powp(acc01, inv_p);
    outh[(size_t)n_hi * NROW + m_lo] = 1.0f - 0.5f * powp(acc10, inv_p);
    outh[(size_t)n_hi * NROW + m_hi] = 1.0f - 0.5f * powp(acc11, inv_p);
}

extern "C" void kernel_launch(void* const* d_in, const int* in_sizes, int n_in,
                              void* d_out, int out_size, void* d_ws, size_t ws_size,
                              hipStream_t stream) {
    const float* A     = (const float*)d_in[0];
    const float* B     = (const float*)d_in[1];
    const float* p_raw = (const float*)d_in[2];
    float* out = (float*)d_out;
    float* ws  = (float*)d_ws;   // [8192][64] normalized rows: An then Bn (2 MB)

    lp_norm_kernel<<<dim3(2048), dim3(256), 0, stream>>>(A, B, p_raw, ws);
    lp_pair_kernel<<<dim3(16, 16, 8), dim3(256), 0, stream>>>(ws, p_raw, out);
}